// Round 9
// baseline (2391.508 us; speedup 1.0000x reference)
//
#include <hip/hip_runtime.h>
#include <cstdint>

typedef float f32x4 __attribute__((ext_vector_type(4)));
typedef __bf16 bf16x8 __attribute__((ext_vector_type(8)));
typedef __bf16 bf16x4 __attribute__((ext_vector_type(4)));

#define NB 512

// Problem constants
// group a: M=512,  DM=512, DI=1024, R=32, P=8,  KS=8,  Lb=256
// group b: M=1024, DM=256, DI=512,  R=16, P=16, KS=4,  Lb=512

struct LayerP {
    const float* src; const __bf16* w_in;
    const float* convw; const float* convb;
    const __bf16* w_xp; const float* dtw; const float* dtb;
    const float* Alog; const float* Dp; const __bf16* w_out;
    float* dst; const float* resid;
    int M, DM, DI, R, P, KS, Lb, tr;
};

struct MegaP {
    unsigned* bar;                    // [cnt, gen]
    float *xz, *xi, *xdbl, *dtbuf, *y, *pk, *wsA, *wsB;
    // plain cvt segments (f32 -> bf16), sizes multiple of 4
    const float* cs[5]; __bf16* cd[5]; int cn[5];
    // padded xproj for group b: (2,48,512) -> (2,64,512)
    const float* xpb; __bf16* xpb_d;
    LayerP L[4];
};

__device__ __forceinline__ void gbar(unsigned* cnt, unsigned* gen)
{
    __syncthreads();
    if (threadIdx.x == 0) {
        __threadfence();
        unsigned g = __hip_atomic_load(gen, __ATOMIC_RELAXED, __HIP_MEMORY_SCOPE_AGENT);
        unsigned old = __hip_atomic_fetch_add(cnt, 1u, __ATOMIC_ACQ_REL, __HIP_MEMORY_SCOPE_AGENT);
        if (old == (unsigned)(NB - 1)) {
            __hip_atomic_store(cnt, 0u, __ATOMIC_RELAXED, __HIP_MEMORY_SCOPE_AGENT);
            __hip_atomic_fetch_add(gen, 1u, __ATOMIC_RELEASE, __HIP_MEMORY_SCOPE_AGENT);
        } else {
            while (__hip_atomic_load(gen, __ATOMIC_RELAXED, __HIP_MEMORY_SCOPE_AGENT) == g)
                __builtin_amdgcn_s_sleep(2);
        }
    }
    __syncthreads();
    __threadfence();
}

// ---- 64x64 MFMA GEMM tile: C[bm:+64, bn:+64] += A(M,K) @ W(N,K)^T ----
__device__ __forceinline__ void gemm_tile(
    const float* __restrict__ A, const __bf16* __restrict__ W,
    float* __restrict__ C, const float* __restrict__ resid,
    int K, int N, int Lb, int tr, int bm, int bn,
    __bf16* sA, __bf16* sW)
{
    const int tid = threadIdx.x;
    const int lane = tid & 63, wv = tid >> 6;
    const int m_off = (wv & 1) * 32, n_off = (wv >> 1) * 32;
    const int fr = lane & 15, fq = lane >> 4;
    f32x4 acc[2][2] = {};

    for (int k0 = 0; k0 < K; k0 += 64) {
#pragma unroll
        for (int i = 0; i < 2; ++i) {
            const int cid = i * 256 + tid;
            const int row = cid >> 3, kc = cid & 7;
            const int slot = kc ^ (row & 7);
            const float* sa = A + (size_t)(bm + row) * K + k0 + kc * 8;
            f32x4 v0 = *(const f32x4*)sa;
            f32x4 v1 = *(const f32x4*)(sa + 4);
            bf16x8 ab;
#pragma unroll
            for (int j = 0; j < 4; ++j) { ab[j] = (__bf16)v0[j]; ab[4 + j] = (__bf16)v1[j]; }
            *(bf16x8*)&sA[row * 64 + slot * 8] = ab;
            *(bf16x8*)&sW[row * 64 + slot * 8] =
                *(const bf16x8*)(W + (size_t)(bn + row) * K + k0 + kc * 8);
        }
        __syncthreads();
#pragma unroll
        for (int ks = 0; ks < 2; ++ks) {
            const int kc = ks * 4 + fq;
            const int r0 = m_off + fr, r1 = m_off + 16 + fr;
            const int c0 = n_off + fr, c1 = n_off + 16 + fr;
            bf16x8 a0 = *(const bf16x8*)&sA[r0 * 64 + (kc ^ (r0 & 7)) * 8];
            bf16x8 a1 = *(const bf16x8*)&sA[r1 * 64 + (kc ^ (r1 & 7)) * 8];
            bf16x8 b0 = *(const bf16x8*)&sW[c0 * 64 + (kc ^ (c0 & 7)) * 8];
            bf16x8 b1 = *(const bf16x8*)&sW[c1 * 64 + (kc ^ (c1 & 7)) * 8];
            acc[0][0] = __builtin_amdgcn_mfma_f32_16x16x32_bf16(a0, b0, acc[0][0], 0, 0, 0);
            acc[0][1] = __builtin_amdgcn_mfma_f32_16x16x32_bf16(a0, b1, acc[0][1], 0, 0, 0);
            acc[1][0] = __builtin_amdgcn_mfma_f32_16x16x32_bf16(a1, b0, acc[1][0], 0, 0, 0);
            acc[1][1] = __builtin_amdgcn_mfma_f32_16x16x32_bf16(a1, b1, acc[1][1], 0, 0, 0);
        }
        __syncthreads();
    }
    if (!tr) {
#pragma unroll
        for (int i = 0; i < 2; ++i)
#pragma unroll
            for (int j = 0; j < 2; ++j)
#pragma unroll
                for (int r = 0; r < 4; ++r)
                    C[(size_t)(bm + m_off + i * 16 + fq * 4 + r) * N
                      + bn + n_off + j * 16 + fr] = acc[i][j][r];
    } else {
#pragma unroll
        for (int i = 0; i < 2; ++i)
#pragma unroll
            for (int j = 0; j < 2; ++j) {
                const int gn = bn + n_off + j * 16 + fr;
#pragma unroll
                for (int r = 0; r < 4; ++r) {
                    const int gm = bm + m_off + i * 16 + fq * 4 + r;
                    const int b = gm / Lb, t = gm - b * Lb;
                    const size_t o = ((size_t)(b * N + gn)) * Lb + t;
                    C[o] = acc[i][j][r] + (resid ? resid[o] : 0.f);
                }
            }
    }
}

__global__ __launch_bounds__(256)
void mega(MegaP p)
{
    __shared__ __bf16 sA[64 * 64];
    __shared__ __bf16 sW[64 * 64];
    unsigned* cnt = p.bar;
    unsigned* gen = p.bar + 1;
    const int tid = threadIdx.x;
    const int bid = blockIdx.x;
    const int gtid = bid * 256 + tid;

    // ---------------- phase 0: weight conversions ----------------
    {
        int tot = 0;
#pragma unroll
        for (int sgm = 0; sgm < 5; ++sgm) tot += p.cn[sgm];
        const int nvec = tot / 4;
        for (int i = gtid; i < nvec; i += NB * 256) {
            int idx = i * 4, sgm = 0, off = idx;
            while (off >= p.cn[sgm]) { off -= p.cn[sgm]; ++sgm; }
            f32x4 v = *(const f32x4*)(p.cs[sgm] + off);
            bf16x4 o;
#pragma unroll
            for (int j = 0; j < 4; ++j) o[j] = (__bf16)v[j];
            *(bf16x4*)(p.cd[sgm] + off) = o;
        }
        for (int i = gtid; i < 2 * 64 * 512; i += NB * 256) {
            const int c = i & 511, r = (i >> 9) & 63, l = i >> 15;
            float v = (r < 48) ? p.xpb[((size_t)l * 48 + r) * 512 + c] : 0.f;
            p.xpb_d[i] = (__bf16)v;
        }
    }
    gbar(cnt, gen);

    for (int k = 0; k < 4; ++k) {
        const LayerP L = p.L[k];
        const int M = L.M, DM = L.DM, DI = L.DI, R = L.R, P = L.P, KS = L.KS, Lb = L.Lb;
        const int N2 = 2 * DI;

        // ---------------- in_proj: xz = src @ w_in^T ----------------
        {
            const int ncols = N2 / 64;
            const int nj = (M / 64) * ncols;
            for (int j = bid; j < nj; j += NB)
                gemm_tile(L.src, L.w_in, p.xz, nullptr, DM, N2, Lb, 0,
                          (j / ncols) * 64, (j % ncols) * 64, sA, sW);
        }
        gbar(cnt, gen);

        // ------- fused conv+SiLU + split-K x_proj partials -> pk[ks][M][64] -------
        {
            const int nstripe = M / 64;
            const int nj = KS * nstripe;
            const int KC = DI / KS;
            for (int j = bid; j < nj; j += NB) {
                const int ks_ = j % KS, stripe = j / KS;
                const int bm = stripe * 64;
                const int kb = ks_ * KC;
                const int lane = tid & 63, wv = tid >> 6;
                const int m_off = (wv & 1) * 32, n_off = (wv >> 1) * 32;
                const int fr = lane & 15, fq = lane >> 4;
                const int b = bm / Lb;
                const int tbase = bm - b * Lb;
                f32x4 acc[2][2] = {};

                for (int k0 = kb; k0 < kb + KC; k0 += 64) {
#pragma unroll
                    for (int i = 0; i < 2; ++i) {
                        const int cid = i * 256 + tid;
                        const int row = cid >> 3, kc = cid & 7;
                        const int slot = kc ^ (row & 7);
                        const int d0 = k0 + kc * 8;
                        const int t = tbase + row;
                        f32x4 a0 = *(const f32x4*)&L.convb[d0];
                        f32x4 a1 = *(const f32x4*)&L.convb[d0 + 4];
                        f32x4 wc[8];
#pragma unroll
                        for (int cch = 0; cch < 8; ++cch)
                            wc[cch] = *(const f32x4*)&L.convw[(size_t)(d0 + cch) * 4];
#pragma unroll
                        for (int jj = 0; jj < 4; ++jj) {
                            const int tt = t - 3 + jj;
                            if (tt >= 0) {
                                const float* src = p.xz + (size_t)(b * Lb + tt) * N2 + d0;
                                f32x4 v0 = *(const f32x4*)src;
                                f32x4 v1 = *(const f32x4*)(src + 4);
#pragma unroll
                                for (int cch = 0; cch < 4; ++cch) {
                                    a0[cch] = fmaf(wc[cch][jj], v0[cch], a0[cch]);
                                    a1[cch] = fmaf(wc[4 + cch][jj], v1[cch], a1[cch]);
                                }
                            }
                        }
                        f32x4 r0v, r1v; bf16x8 ab;
#pragma unroll
                        for (int cch = 0; cch < 4; ++cch) {
                            const float u0 = a0[cch], u1 = a1[cch];
                            const float s0 = u0 / (1.f + __expf(-u0));
                            const float s1 = u1 / (1.f + __expf(-u1));
                            r0v[cch] = s0; r1v[cch] = s1;
                            ab[cch] = (__bf16)s0; ab[4 + cch] = (__bf16)s1;
                        }
                        const size_t mrow = (size_t)(bm + row);
                        *(f32x4*)&p.xi[mrow * DI + d0] = r0v;
                        *(f32x4*)&p.xi[mrow * DI + d0 + 4] = r1v;
                        *(bf16x8*)&sA[row * 64 + slot * 8] = ab;
                        *(bf16x8*)&sW[row * 64 + slot * 8] =
                            *(const bf16x8*)(L.w_xp + (size_t)row * DI + k0 + kc * 8);
                    }
                    __syncthreads();
#pragma unroll
                    for (int ksu = 0; ksu < 2; ++ksu) {
                        const int kc = ksu * 4 + fq;
                        const int r0 = m_off + fr, r1 = m_off + 16 + fr;
                        const int c0 = n_off + fr, c1 = n_off + 16 + fr;
                        bf16x8 a0 = *(const bf16x8*)&sA[r0 * 64 + (kc ^ (r0 & 7)) * 8];
                        bf16x8 a1 = *(const bf16x8*)&sA[r1 * 64 + (kc ^ (r1 & 7)) * 8];
                        bf16x8 b0 = *(const bf16x8*)&sW[c0 * 64 + (kc ^ (c0 & 7)) * 8];
                        bf16x8 b1 = *(const bf16x8*)&sW[c1 * 64 + (kc ^ (c1 & 7)) * 8];
                        acc[0][0] = __builtin_amdgcn_mfma_f32_16x16x32_bf16(a0, b0, acc[0][0], 0, 0, 0);
                        acc[0][1] = __builtin_amdgcn_mfma_f32_16x16x32_bf16(a0, b1, acc[0][1], 0, 0, 0);
                        acc[1][0] = __builtin_amdgcn_mfma_f32_16x16x32_bf16(a1, b0, acc[1][0], 0, 0, 0);
                        acc[1][1] = __builtin_amdgcn_mfma_f32_16x16x32_bf16(a1, b1, acc[1][1], 0, 0, 0);
                    }
                    __syncthreads();
                }
                float* out = p.pk + (size_t)ks_ * M * 64;
#pragma unroll
                for (int i = 0; i < 2; ++i)
#pragma unroll
                    for (int jj = 0; jj < 2; ++jj)
#pragma unroll
                        for (int r = 0; r < 4; ++r)
                            out[(size_t)(bm + m_off + i * 16 + fq * 4 + r) * 64
                                + n_off + jj * 16 + fr] = acc[i][jj][r];
            }
        }
        gbar(cnt, gen);

        // ------- xp_finish: reduce partials -> xdbl f32; dt = softplus(xdbl@dtw^T+b) -------
        {
            float* sfin = (float*)sA;     // 4 x 64 f32
            const int nj = M / 4;
            const int rl = tid >> 6, lane = tid & 63;
            for (int j = bid; j < nj; j += NB) {
                const int m = j * 4 + rl;
                float v = 0.f;
                for (int ks_ = 0; ks_ < KS; ++ks_)
                    v += p.pk[(size_t)ks_ * M * 64 + (size_t)m * 64 + lane];
                p.xdbl[(size_t)m * 64 + lane] = v;
                sfin[rl * 64 + lane] = v;
                __syncthreads();
                const int per = DI / 64;
                for (int o = 0; o < per; ++o) {
                    const int d = lane + o * 64;
                    const float* wr = L.dtw + (size_t)d * R;
                    float a2 = L.dtb[d];
                    for (int r = 0; r < R; ++r) a2 = fmaf(sfin[rl * 64 + r], wr[r], a2);
                    p.dtbuf[(size_t)m * DI + d] = fmaxf(a2, 0.f) + log1pf(__expf(-fabsf(a2)));
                }
                __syncthreads();
            }
        }
        gbar(cnt, gen);

        // ---------------- scan phase 1 ----------------
        {
            const int s = tid & 15, dl = tid >> 4;
            const int nDB = DI >> 4, cpb = P * nDB;
            const int nj = 2 * cpb;
            for (int j = bid; j < nj; j += NB) {
                const int b = j / cpb, rem = j % cpb, c = rem / nDB;
                const int d = (rem % nDB) * 16 + dl;
                const float Av = -__expf(L.Alog[(size_t)d * 16 + s]);
                float h = 0.f, sdt = 0.f;
                const size_t rowbase = (size_t)b * Lb + c * 32;
#pragma unroll 4
                for (int t = 0; t < 32; ++t) {
                    const size_t m = rowbase + t;
                    const float dtv = p.dtbuf[m * DI + d];
                    const float xv  = p.xi[m * DI + d];
                    const float Bv  = p.xdbl[m * 64 + R + s];
                    h = fmaf(__expf(dtv * Av), h, dtv * Bv * xv);
                    sdt += dtv;
                }
                const size_t o = ((size_t)(b * P + c) * DI + d) * 16 + s;
                p.wsA[o] = __expf(sdt * Av);
                p.wsB[o] = h;
            }
        }
        gbar(cnt, gen);

        // ---------------- scan phases 2+3 ----------------
        {
            const int s = tid & 15, dl = tid >> 4;
            const int nDB = DI >> 4, cpb = P * nDB;
            const int nj = 2 * cpb;
            for (int j = bid; j < nj; j += NB) {
                const int b = j / cpb, rem = j % cpb, c = rem / nDB;
                const int d = (rem % nDB) * 16 + dl;
                const float Av = -__expf(L.Alog[(size_t)d * 16 + s]);
                const float Dv = L.Dp[d];
                float h = 0.f;
                for (int cc = 0; cc < c; ++cc) {
                    const size_t oc = ((size_t)(b * P + cc) * DI + d) * 16 + s;
                    h = fmaf(p.wsA[oc], h, p.wsB[oc]);
                }
                const size_t rowbase = (size_t)b * Lb + c * 32;
#pragma unroll 2
                for (int t = 0; t < 32; ++t) {
                    const size_t m = rowbase + t;
                    const float dtv = p.dtbuf[m * DI + d];
                    const float xv  = p.xi[m * DI + d];
                    const float Bv  = p.xdbl[m * 64 + R + s];
                    const float Cv  = p.xdbl[m * 64 + R + 16 + s];
                    h = fmaf(__expf(dtv * Av), h, dtv * Bv * xv);
                    float pp = h * Cv;
                    pp += __shfl_xor(pp, 1, 16);
                    pp += __shfl_xor(pp, 2, 16);
                    pp += __shfl_xor(pp, 4, 16);
                    pp += __shfl_xor(pp, 8, 16);
                    if (s == 0) {
                        const float zv = p.xz[m * (size_t)N2 + DI + d];
                        const float sig = __fdividef(zv, 1.f + __expf(-zv));
                        p.y[m * DI + d] = (pp + Dv * xv) * sig;
                    }
                }
            }
        }
        gbar(cnt, gen);

        // ---------------- out_proj ----------------
        {
            const int ncols = DM / 64;
            const int nj = (M / 64) * ncols;
            for (int j = bid; j < nj; j += NB)
                gemm_tile(p.y, L.w_out, L.dst, L.resid, DI, DM, Lb, L.tr,
                          (j / ncols) * 64, (j % ncols) * 64, sA, sW);
        }
        if (k < 3) gbar(cnt, gen);
    }
}

extern "C" void kernel_launch(void* const* d_in, const int* in_sizes, int n_in,
                              void* d_out, int out_size, void* d_ws, size_t ws_size,
                              hipStream_t stream)
{
    const float* x       = (const float*)d_in[0];
    const float* a_in_w  = (const float*)d_in[1];
    const float* a_convw = (const float*)d_in[2];
    const float* a_convb = (const float*)d_in[3];
    const float* a_xproj = (const float*)d_in[4];
    const float* a_dtw   = (const float*)d_in[5];
    const float* a_dtb   = (const float*)d_in[6];
    const float* a_Alog  = (const float*)d_in[7];
    const float* a_Dp    = (const float*)d_in[8];
    const float* a_outw  = (const float*)d_in[9];
    const float* b_in_w  = (const float*)d_in[10];
    const float* b_convw = (const float*)d_in[11];
    const float* b_convb = (const float*)d_in[12];
    const float* b_xproj = (const float*)d_in[13];
    const float* b_dtw   = (const float*)d_in[14];
    const float* b_dtb   = (const float*)d_in[15];
    const float* b_Alog  = (const float*)d_in[16];
    const float* b_Dp    = (const float*)d_in[17];
    const float* b_outw  = (const float*)d_in[18];

    float* ws = (float*)d_ws;
    unsigned* bar   = (unsigned*)ws;       // 64 f32 reserved
    float* buf_x    = ws + 64;             // 262144
    float* buf_x2   = buf_x + 262144;      // 262144
    float* buf_xz   = buf_x2 + 262144;     // 1048576
    float* buf_xi   = buf_xz + 1048576;    // 524288
    float* buf_xd   = buf_xi + 524288;     // 65536
    float* buf_dt   = buf_xd + 65536;      // 524288
    float* buf_y    = buf_dt + 524288;     // 524288
    float* buf_pk   = buf_y + 524288;      // 262144
    float* buf_wsA  = buf_pk + 262144;     // 262144
    float* buf_wsB  = buf_wsA + 262144;    // 262144
    __bf16* wb       = (__bf16*)(buf_wsB + 262144);
    __bf16* wb_a_in  = wb;                 // 2097152
    __bf16* wb_a_out = wb_a_in + 2097152;  // 1048576
    __bf16* wb_b_in  = wb_a_out + 1048576; // 524288
    __bf16* wb_b_out = wb_b_in + 524288;   // 262144
    __bf16* wb_xp_a  = wb_b_out + 262144;  // 131072 (2,64,1024)
    __bf16* wb_xp_b  = wb_xp_a + 131072;   // 65536  (2,64,512) padded

    MegaP p;
    p.bar = bar;
    p.xz = buf_xz; p.xi = buf_xi; p.xdbl = buf_xd; p.dtbuf = buf_dt;
    p.y = buf_y; p.pk = buf_pk; p.wsA = buf_wsA; p.wsB = buf_wsB;
    p.cs[0] = a_in_w;  p.cd[0] = wb_a_in;  p.cn[0] = 2097152;
    p.cs[1] = a_outw;  p.cd[1] = wb_a_out; p.cn[1] = 1048576;
    p.cs[2] = b_in_w;  p.cd[2] = wb_b_in;  p.cn[2] = 524288;
    p.cs[3] = b_outw;  p.cd[3] = wb_b_out; p.cn[3] = 262144;
    p.cs[4] = a_xproj; p.cd[4] = wb_xp_a;  p.cn[4] = 131072;
    p.xpb = b_xproj;   p.xpb_d = wb_xp_b;

    for (int k = 0; k < 2; ++k) {
        LayerP& L = p.L[k];
        L.M = 512; L.DM = 512; L.DI = 1024; L.R = 32; L.P = 8; L.KS = 8; L.Lb = 256;
        L.src = (k == 0) ? x : buf_x;
        L.w_in = wb_a_in + (size_t)k * 2 * 1024 * 512;
        L.convw = a_convw + (size_t)k * 1024 * 4;
        L.convb = a_convb + (size_t)k * 1024;
        L.w_xp = wb_xp_a + (size_t)k * 64 * 1024;
        L.dtw = a_dtw + (size_t)k * 1024 * 32;
        L.dtb = a_dtb + (size_t)k * 1024;
        L.Alog = a_Alog + (size_t)k * 1024 * 16;
        L.Dp = a_Dp + (size_t)k * 1024;
        L.w_out = wb_a_out + (size_t)k * 512 * 1024;
        L.dst = (k == 0) ? buf_x : buf_x2;
        L.resid = nullptr;
        L.tr = (k == 1) ? 1 : 0;
    }
    for (int k = 0; k < 2; ++k) {
        LayerP& L = p.L[2 + k];
        L.M = 1024; L.DM = 256; L.DI = 512; L.R = 16; L.P = 16; L.KS = 4; L.Lb = 512;
        L.src = (k == 0) ? buf_x2 : buf_x;
        L.w_in = wb_b_in + (size_t)k * 2 * 512 * 256;
        L.convw = b_convw + (size_t)k * 512 * 4;
        L.convb = b_convb + (size_t)k * 512;
        L.w_xp = wb_xp_b + (size_t)k * 64 * 512;
        L.dtw = b_dtw + (size_t)k * 512 * 16;
        L.dtb = b_dtb + (size_t)k * 512;
        L.Alog = b_Alog + (size_t)k * 512 * 16;
        L.Dp = b_Dp + (size_t)k * 512;
        L.w_out = wb_b_out + (size_t)k * 256 * 512;
        L.dst = (k == 0) ? buf_x : (float*)d_out;
        L.resid = (k == 1) ? x : nullptr;
        L.tr = (k == 1) ? 1 : 0;
    }

    hipMemsetAsync(bar, 0, 8, stream);
    mega<<<NB, 256, 0, stream>>>(p);
}